// Round 8
// baseline (1051.815 us; speedup 1.0000x reference)
//
#include <hip/hip_runtime.h>

#define BB 256
#define TT 1024
#define KK 64
#define CS 65   // column stride in floats: bank (j+i)%32 -> 2 lanes/bank = free

// One block per batch item, 512 threads = 8 waves.
// Chains are SINGLE-WAVE: lane j owns state j; x broadcast via v_readlane;
// the 64x64 transition matrix lives in LDS, COLUMN-major with stride 65:
// lane j reads its private column j with conflict-free ds_read2_b32 pairs.
//   wave0: forward (exp-domain, renorm every 8 steps)  -- reads Ecol
//   wave1: Viterbi max-only + checkpoint every 32 steps -- reads Ccol
//   wave2: gold-path score
//   waves 3-7: park at the phase barrier
// Phase B (all 8 waves): recompute 32-step segments from checkpoints with the
// tie-exact argmax tournament (strict >, lower index wins), reading Ccol.
//
// LESSON r2-r7: the compiler refuses to keep a 64-deep loop-invariant column
// in VGPRs (VGPR_Count 52-56 across 5 attempts; per-step global re-reads on
// the serial chain). Fix: stop needing residency -- columns in LDS, and the
// per-step base index laundered through asm volatile so the loads can never
// be hoisted back into a 64-live register demand.
__device__ __forceinline__ float rlane(float x, int i) {
  return __int_as_float(__builtin_amdgcn_readlane(__float_as_int(x), i));
}
#define RL(S, i) rlane(S, i)

__device__ __forceinline__ float wavemax(float v) {
#pragma unroll
  for (int off = 1; off <= 32; off <<= 1) v = fmaxf(v, __shfl_xor(v, off));
  return v;
}

// ---- forward: 4-way accumulated dot; E operand straight from LDS ----
#define FQ4(S, a, b, c, d) \
  q0 = __builtin_fmaf(RL(S, a), Ecol[eb + (a)], q0); \
  q1 = __builtin_fmaf(RL(S, b), Ecol[eb + (b)], q1); \
  q2 = __builtin_fmaf(RL(S, c), Ecol[eb + (c)], q2); \
  q3 = __builtin_fmaf(RL(S, d), Ecol[eb + (d)], q3);
#define FQALL(S) \
  FQ4(S, 0, 1, 2, 3)     FQ4(S, 4, 5, 6, 7)     FQ4(S, 8, 9, 10, 11) \
  FQ4(S, 12, 13, 14, 15) FQ4(S, 16, 17, 18, 19) FQ4(S, 20, 21, 22, 23) \
  FQ4(S, 24, 25, 26, 27) FQ4(S, 28, 29, 30, 31) FQ4(S, 32, 33, 34, 35) \
  FQ4(S, 36, 37, 38, 39) FQ4(S, 40, 41, 42, 43) FQ4(S, 44, 45, 46, 47) \
  FQ4(S, 48, 49, 50, 51) FQ4(S, 52, 53, 54, 55) FQ4(S, 56, 57, 58, 59) \
  FQ4(S, 60, 61, 62, 63)

#define FWD_STEP(T_, E_, M_) { \
  int eb = jb65; asm volatile("" : "+v"(eb));  /* opaque base: no hoisting */ \
  float q0 = 0.f, q1 = 0.f, q2 = 0.f, q3 = 0.f; \
  FQALL(x) \
  float q = (q0 + q1) + (q2 + q3); \
  q *= (E_); \
  q = (M_) ? q : x; \
  if (((T_) & 7) == 0) {  /* renorm by max of PRE-update s (wave-uniform) */ \
    float gm = wavemax(x); \
    q *= __builtin_amdgcn_rcpf(gm); \
    offset += __logf(gm); \
  } \
  x = q; }

#define FWD_ITER(K_, EP_, MP_) { \
  int t = tb + (K_); \
  float e = EP_; int m = MP_; \
  int tpre = t + 4; if (tpre > TT - 1) tpre = TT - 1; \
  EP_ = __expf(emb[(size_t)tpre * KK + j]); \
  MP_ = mrow[tpre]; \
  FWD_STEP(t, e, m) }

// ---- viterbi max-only (fmax is exactly associative; tree shape free) ----
#define VQ(g, a, b, c, d) float vm##g; { \
  float v0 = RL(x, a) + Ccol[cb + (a)]; \
  float v1 = RL(x, b) + Ccol[cb + (b)]; \
  float v2 = RL(x, c) + Ccol[cb + (c)]; \
  float v3 = RL(x, d) + Ccol[cb + (d)]; \
  vm##g = fmaxf(fmaxf(v0, v1), fmaxf(v2, v3)); }

#define VIT_STEP(T_, E_, M_) { \
  int cb = jb65; asm volatile("" : "+v"(cb)); \
  VQ(0, 0, 1, 2, 3)      VQ(1, 4, 5, 6, 7)      VQ(2, 8, 9, 10, 11) \
  VQ(3, 12, 13, 14, 15)  VQ(4, 16, 17, 18, 19)  VQ(5, 20, 21, 22, 23) \
  VQ(6, 24, 25, 26, 27)  VQ(7, 28, 29, 30, 31)  VQ(8, 32, 33, 34, 35) \
  VQ(9, 36, 37, 38, 39)  VQ(10, 40, 41, 42, 43) VQ(11, 44, 45, 46, 47) \
  VQ(12, 48, 49, 50, 51) VQ(13, 52, 53, 54, 55) VQ(14, 56, 57, 58, 59) \
  VQ(15, 60, 61, 62, 63) \
  float b0 = fmaxf(vm0, vm1),   b1 = fmaxf(vm2, vm3); \
  float b2 = fmaxf(vm4, vm5),   b3 = fmaxf(vm6, vm7); \
  float b4 = fmaxf(vm8, vm9),   b5 = fmaxf(vm10, vm11); \
  float b6 = fmaxf(vm12, vm13), b7 = fmaxf(vm14, vm15); \
  float best = fmaxf(fmaxf(fmaxf(b0, b1), fmaxf(b2, b3)), \
                     fmaxf(fmaxf(b4, b5), fmaxf(b6, b7))); \
  float nd = (M_) ? (best + (E_)) : x; \
  if (((T_) & 31) == 0) ckpt[(T_) >> 5][j] = nd; \
  x = nd; }

#define VIT_ITER(K_, EP_, MP_) { \
  int t = tb + (K_); \
  float e = EP_; int m = MP_; \
  int tpre = t + 4; if (tpre > TT - 1) tpre = TT - 1; \
  EP_ = emb[(size_t)tpre * KK + j]; \
  MP_ = mrow[tpre]; \
  VIT_STEP(t, e, m) }

// ---- phase-B tie-exact argmax over 8 (strict >, lower index wins) ----
#define AG(i0, i1, i2, i3, i4, i5, i6, i7) { \
  float v0 = RL(x2, i0) + Ccol[db + (i0)]; \
  float v1 = RL(x2, i1) + Ccol[db + (i1)]; \
  float v2 = RL(x2, i2) + Ccol[db + (i2)]; \
  float v3 = RL(x2, i3) + Ccol[db + (i3)]; \
  float v4 = RL(x2, i4) + Ccol[db + (i4)]; \
  float v5 = RL(x2, i5) + Ccol[db + (i5)]; \
  float v6 = RL(x2, i6) + Ccol[db + (i6)]; \
  float v7 = RL(x2, i7) + Ccol[db + (i7)]; \
  bool p0 = v1 > v0; float a0 = p0 ? v1 : v0; int n0 = p0 ? (i1) : (i0); \
  bool p1 = v3 > v2; float a1 = p1 ? v3 : v2; int n1 = p1 ? (i3) : (i2); \
  bool p2 = v5 > v4; float a2 = p2 ? v5 : v4; int n2 = p2 ? (i5) : (i4); \
  bool p3 = v7 > v6; float a3 = p3 ? v7 : v6; int n3 = p3 ? (i7) : (i6); \
  bool r0 = a1 > a0; float bb0 = r0 ? a1 : a0; int m0 = r0 ? n1 : n0; \
  bool r1 = a3 > a2; float bb1 = r1 ? a3 : a2; int m1 = r1 ? n3 : n2; \
  bool s0 = bb1 > bb0; float gg = s0 ? bb1 : bb0; int w0 = s0 ? m1 : m0; \
  bool u0 = gg > bv; bv = u0 ? gg : bv; bi = u0 ? w0 : bi; }

__global__ __launch_bounds__(512)
__attribute__((amdgpu_waves_per_eu(1, 2)))
void crf_mega_kernel(
    const float* __restrict__ em, const int* __restrict__ mask,
    const float* __restrict__ trans, const int* __restrict__ tags,
    float* __restrict__ out_dec, float* ll_sum, int* match, int* maskSum) {

  __shared__ float Ecol[KK * CS];               // exp(T) columns, stride 65
  __shared__ float Ccol[KK * CS];               // raw T columns, stride 65
  __shared__ __align__(16) float ckpt[33][KK];  // delta checkpoints (+final in [32])
  __shared__ unsigned char mrow[TT];
  __shared__ unsigned char bpl[TT][KK];         // backpointers (64 KB)
  __shared__ unsigned char segm[32][KK];
  __shared__ unsigned char bs[40];
  __shared__ int redm[32];

  const int b = blockIdx.x;
  const int tid = threadIdx.x;
  const int wv = tid >> 6;
  const int j = tid & 63;
  const int jb65 = j * CS;

  const float* emb = em + (size_t)b * TT * KK;
  const int* mb = mask + (size_t)b * TT;
  const int* tgb = tags + (size_t)b * TT;

  for (int t = tid; t < TT; t += 512) mrow[t] = (unsigned char)(mb[t] ? 1 : 0);
  if (wv == 0) {        // fill exp(T) columns (coalesced global row reads)
#pragma unroll 4
    for (int i = 0; i < KK; ++i) Ecol[jb65 + i] = __expf(trans[i * KK + j]);
  } else if (wv == 1) { // fill raw T columns (also used by phase B)
#pragma unroll 4
    for (int i = 0; i < KK; ++i) Ccol[jb65 + i] = trans[i * KK + j];
  }
  __syncthreads();  // B0

  if (wv == 0) {
    // =========================== FORWARD (wave 0) ===========================
    float raw = emb[j];
    float x, offset;
    {  // ---- t = 1 special: exponentiate raw e0 with global max ----
      float m0 = wavemax(raw);
      offset = m0;
      float s = __expf(raw - m0);
      int eb = jb65; asm volatile("" : "+v"(eb));
      float q0 = 0.f, q1 = 0.f, q2 = 0.f, q3 = 0.f;
      FQALL(s)
      float q = (q0 + q1) + (q2 + q3);
      q *= __expf(emb[KK + j]);
      x = mrow[1] ? q : s;
    }
    float ep0 = __expf(emb[(size_t)2 * KK + j]);
    float ep1 = __expf(emb[(size_t)3 * KK + j]);
    float ep2 = __expf(emb[(size_t)4 * KK + j]);
    float ep3 = __expf(emb[(size_t)5 * KK + j]);
    int mp0 = mrow[2], mp1 = mrow[3], mp2 = mrow[4], mp3 = mrow[5];

    for (int tb = 2; tb + 3 <= TT - 1; tb += 4) {
      FWD_ITER(0, ep0, mp0)
      FWD_ITER(1, ep1, mp1)
      FWD_ITER(2, ep2, mp2)
      FWD_ITER(3, ep3, mp3)
    }
    // tail: t = 1022 (slot 0), t = 1023 (slot 1) -- static slot references
    FWD_STEP(TT - 2, ep0, mp0)
    FWD_STEP(TT - 1, ep1, mp1)

    float ssum = x;
#pragma unroll
    for (int off = 1; off <= 32; off <<= 1) ssum += __shfl_xor(ssum, off);
    if (tid == 0) atomicAdd(ll_sum, -(offset + __logf(ssum)));

  } else if (wv == 1) {
    // ====================== VITERBI max-only (wave 1) ======================
    float x = emb[j];
    ckpt[0][j] = x;
    float ep0 = emb[(size_t)1 * KK + j];
    float ep1 = emb[(size_t)2 * KK + j];
    float ep2 = emb[(size_t)3 * KK + j];
    float ep3 = emb[(size_t)4 * KK + j];
    int mp0 = mrow[1], mp1 = mrow[2], mp2 = mrow[3], mp3 = mrow[4];

    for (int tb = 1; tb + 3 <= TT - 1; tb += 4) {
      VIT_ITER(0, ep0, mp0)
      VIT_ITER(1, ep1, mp1)
      VIT_ITER(2, ep2, mp2)
      VIT_ITER(3, ep3, mp3)
    }
    // tail: t = 1021,1022,1023 -> slots 0,1,2
    VIT_STEP(TT - 3, ep0, mp0)
    VIT_STEP(TT - 2, ep1, mp1)
    VIT_STEP(TT - 1, ep2, mp2)

    ckpt[32][j] = x;   // final delta for last-tag argmax

  } else if (wv == 2) {
    // ========================= PATH SCORE (wave 2) =========================
    float acc = 0.f;
    int cnt = 0;
    for (int t = j; t < TT; t += 64) {
      if (mb[t]) {
        int tg = tgb[t];
        acc += emb[(size_t)t * KK + tg];
        cnt += 1;
        if (t >= 1) acc += trans[tgb[t - 1] * KK + tg];
      }
    }
#pragma unroll
    for (int off = 1; off <= 32; off <<= 1) {
      acc += __shfl_xor(acc, off);
      cnt += __shfl_xor(cnt, off);
    }
    if (j == 0) { atomicAdd(ll_sum, acc); atomicAdd(maskSum, cnt); }
  }
  // waves 3-7 fall through.

  __syncthreads();  // B1 — phase boundary (orders Ccol for all waves)

  // ====== PHASE B: per-segment argmax recompute (8 waves x 4 segments) ======
#pragma unroll 1
  for (int kk = 0; kk < 4; ++kk) {
    int s = wv + 8 * kk;
    int tS = 32 * s + 1;
    int tE = (s == 31) ? (TT - 1) : (32 * s + 32);
    float x2 = ckpt[s][j];
    float e_nx = emb[(size_t)tS * KK + j];
#pragma unroll 1
    for (int t = tS; t <= tE; ++t) {
      float e = e_nx;
      if (t < tE) e_nx = emb[(size_t)(t + 1) * KK + j];
      int db = jb65; asm volatile("" : "+v"(db));
      float bv = -__builtin_inff(); int bi = 0;
      AG(0, 1, 2, 3, 4, 5, 6, 7)        AG(8, 9, 10, 11, 12, 13, 14, 15)
      AG(16, 17, 18, 19, 20, 21, 22, 23) AG(24, 25, 26, 27, 28, 29, 30, 31)
      AG(32, 33, 34, 35, 36, 37, 38, 39) AG(40, 41, 42, 43, 44, 45, 46, 47)
      AG(48, 49, 50, 51, 52, 53, 54, 55) AG(56, 57, 58, 59, 60, 61, 62, 63)
      int m = mrow[t];
      float nd = m ? (bv + e) : x2;
      int bp = m ? bi : j;
      bpl[t][j] = (unsigned char)bp;
      x2 = nd;
    }
  }
  __syncthreads();  // B2

  // ---- compose 32-step segment maps (4 chains per thread, ILP) ----
  {
    int j0 = tid & 63;
    int sg = tid >> 6;     // 0..7
    int xs[4]; int tS[4], tE[4];
#pragma unroll
    for (int kk = 0; kk < 4; ++kk) {
      int s = sg + 8 * kk;
      xs[kk] = j0;
      tS[kk] = 32 * s + 1;
      tE[kk] = (s == 31) ? (TT - 1) : (32 * s + 32);
    }
    for (int q = 0; q < 32; ++q) {
#pragma unroll
      for (int kk = 0; kk < 4; ++kk) {
        int t = tE[kk] - q;
        if (t >= tS[kk]) xs[kk] = bpl[t][xs[kk]];
      }
    }
#pragma unroll
    for (int kk = 0; kk < 4; ++kk) segm[sg + 8 * kk][j0] = (unsigned char)xs[kk];
  }
  __syncthreads();  // B3

  if (tid == 0) {   // last_tag argmax (strict >, first max) + boundary walk
    float bd = ckpt[32][0];
    int lt = 0;
    for (int i = 1; i < KK; ++i) {
      float v2 = ckpt[32][i];
      if (v2 > bd) { bd = v2; lt = i; }
    }
    bs[32] = (unsigned char)lt;
    for (int s = 31; s >= 0; --s) bs[s] = segm[s][bs[s + 1]];
  }
  __syncthreads();  // B4

  if (tid < 32) {   // per-segment backtrace
    int s = tid;
    int x = bs[s + 1];
    int cnt = 0;
    int tEnd = (s == 31) ? (TT - 1) : (32 * s + 32);
    if (s == 31) {
      int m = mrow[TT - 1];
      out_dec[(size_t)b * TT + TT - 1] = (float)(m ? x : 0);
      cnt += (m && x == tgb[TT - 1]);
    }
    for (int t = tEnd; t >= 32 * s + 1; --t) {
      x = bpl[t][x];
      int m2 = mrow[t - 1];
      out_dec[(size_t)b * TT + t - 1] = (float)(m2 ? x : 0);
      cnt += (m2 && x == tgb[t - 1]);
    }
    redm[s] = cnt;
  }
  __syncthreads();  // B5
  if (tid == 0) {
    int c = 0;
    for (int s = 0; s < 32; ++s) c += redm[s];
    atomicAdd(match, c);
  }
}

__global__ void finalize_kernel(const float* ll_sum, const int* match,
                                const int* maskSum, float* d_out) {
  d_out[0] = -(*ll_sum) / (float)BB;
  d_out[1 + BB * TT] = (float)(*match) / (float)(*maskSum);
}

extern "C" void kernel_launch(void* const* d_in, const int* in_sizes, int n_in,
                              void* d_out, int out_size, void* d_ws, size_t ws_size,
                              hipStream_t stream) {
  const float* em = (const float*)d_in[0];
  const int* tags = (const int*)d_in[1];
  const int* mask = (const int*)d_in[2];       // bool -> int32 on device
  const float* trans = (const float*)d_in[3];
  float* out = (float*)d_out;

  float* ll_sum = (float*)d_ws;
  int* match = (int*)((char*)d_ws + 4);
  int* maskSum = (int*)((char*)d_ws + 8);

  hipMemsetAsync(d_ws, 0, 12, stream);
  crf_mega_kernel<<<BB, 512, 0, stream>>>(em, mask, trans, tags, out + 1,
                                          ll_sum, match, maskSum);
  finalize_kernel<<<1, 1, 0, stream>>>(ll_sum, match, maskSum, out);
}

// Round 9
// 588.759 us; speedup vs baseline: 1.7865x; 1.7865x over previous
//
#include <hip/hip_runtime.h>

#define BB 256
#define TT 1024
#define KK 64
#define CS 65

// One block per batch item, 512 threads = 8 waves.
//   wave0: forward chain  -- WHOLE LOOP IN ONE ASM BLOCK, E matrix pinned in
//          physical v64-v127 (compiler cannot spill/sink inside one asm)
//   wave1: Viterbi max-only chain -- same, ckpts ds_written every 16 steps
//   wave2: gold-path score (C++)
// Phase B (all 8 waves): tie-exact argmax recompute per 32-step segment (C++,
// LDS Ccol), filling bpl. Then compose/backtrace epilogue (C++, proven).
//
// LESSON r2-r8: every source-level attempt to keep a 64-deep loop-invariant
// column register-resident was refused (VGPR_Count 52-56-88). Explicit
// physical registers inside a single asm block are not negotiable.

__device__ __forceinline__ float rlane(float x, int i) {
  return __int_as_float(__builtin_amdgcn_readlane(__float_as_int(x), i));
}
#define RL(S, i) rlane(S, i)

__device__ __forceinline__ float wavemax(float v) {
#pragma unroll
  for (int off = 1; off <= 32; off <<= 1) v = fmaxf(v, __shfl_xor(v, off));
  return v;
}

// ======================= C++ helpers (head/tail/t1) =======================
#define CFQ4(S, a, b, c, d) \
  q0 = __builtin_fmaf(RL(S, a), Ecol[eb + (a)], q0); \
  q1 = __builtin_fmaf(RL(S, b), Ecol[eb + (b)], q1); \
  q2 = __builtin_fmaf(RL(S, c), Ecol[eb + (c)], q2); \
  q3 = __builtin_fmaf(RL(S, d), Ecol[eb + (d)], q3);
#define CFQALL(S) \
  CFQ4(S, 0, 1, 2, 3)     CFQ4(S, 4, 5, 6, 7)     CFQ4(S, 8, 9, 10, 11) \
  CFQ4(S, 12, 13, 14, 15) CFQ4(S, 16, 17, 18, 19) CFQ4(S, 20, 21, 22, 23) \
  CFQ4(S, 24, 25, 26, 27) CFQ4(S, 28, 29, 30, 31) CFQ4(S, 32, 33, 34, 35) \
  CFQ4(S, 36, 37, 38, 39) CFQ4(S, 40, 41, 42, 43) CFQ4(S, 44, 45, 46, 47) \
  CFQ4(S, 48, 49, 50, 51) CFQ4(S, 52, 53, 54, 55) CFQ4(S, 56, 57, 58, 59) \
  CFQ4(S, 60, 61, 62, 63)

#define CFWD_STEP(T_, E_, M_) { \
  int eb = jb65; asm volatile("" : "+v"(eb)); \
  float q0 = 0.f, q1 = 0.f, q2 = 0.f, q3 = 0.f; \
  CFQALL(x) \
  float q = (q0 + q1) + (q2 + q3); \
  q *= (E_); \
  q = (M_) ? q : x; \
  if (((T_) & 7) == 0) { \
    float gm = wavemax(x); \
    q *= __builtin_amdgcn_rcpf(gm); \
    offset += __logf(gm); \
  } \
  x = q; }

#define CVQ(g, a, b, c, d) float vm##g; { \
  float v0 = RL(x, a) + Ccol[cb + (a)]; \
  float v1 = RL(x, b) + Ccol[cb + (b)]; \
  float v2 = RL(x, c) + Ccol[cb + (c)]; \
  float v3 = RL(x, d) + Ccol[cb + (d)]; \
  vm##g = fmaxf(fmaxf(v0, v1), fmaxf(v2, v3)); }

#define CVIT_STEP(T_, E_, M_) { \
  int cb = jb65; asm volatile("" : "+v"(cb)); \
  CVQ(0, 0, 1, 2, 3)      CVQ(1, 4, 5, 6, 7)      CVQ(2, 8, 9, 10, 11) \
  CVQ(3, 12, 13, 14, 15)  CVQ(4, 16, 17, 18, 19)  CVQ(5, 20, 21, 22, 23) \
  CVQ(6, 24, 25, 26, 27)  CVQ(7, 28, 29, 30, 31)  CVQ(8, 32, 33, 34, 35) \
  CVQ(9, 36, 37, 38, 39)  CVQ(10, 40, 41, 42, 43) CVQ(11, 44, 45, 46, 47) \
  CVQ(12, 48, 49, 50, 51) CVQ(13, 52, 53, 54, 55) CVQ(14, 56, 57, 58, 59) \
  CVQ(15, 60, 61, 62, 63) \
  float b0 = fmaxf(vm0, vm1),   b1 = fmaxf(vm2, vm3); \
  float b2 = fmaxf(vm4, vm5),   b3 = fmaxf(vm6, vm7); \
  float b4 = fmaxf(vm8, vm9),   b5 = fmaxf(vm10, vm11); \
  float b6 = fmaxf(vm12, vm13), b7 = fmaxf(vm14, vm15); \
  float best = fmaxf(fmaxf(fmaxf(b0, b1), fmaxf(b2, b3)), \
                     fmaxf(fmaxf(b4, b5), fmaxf(b6, b7))); \
  float nd = (M_) ? (best + (E_)) : x; \
  x = nd; }

#define AG(i0, i1, i2, i3, i4, i5, i6, i7) { \
  float v0 = RL(x2, i0) + Ccol[db + (i0)]; \
  float v1 = RL(x2, i1) + Ccol[db + (i1)]; \
  float v2 = RL(x2, i2) + Ccol[db + (i2)]; \
  float v3 = RL(x2, i3) + Ccol[db + (i3)]; \
  float v4 = RL(x2, i4) + Ccol[db + (i4)]; \
  float v5 = RL(x2, i5) + Ccol[db + (i5)]; \
  float v6 = RL(x2, i6) + Ccol[db + (i6)]; \
  float v7 = RL(x2, i7) + Ccol[db + (i7)]; \
  bool p0 = v1 > v0; float a0 = p0 ? v1 : v0; int n0 = p0 ? (i1) : (i0); \
  bool p1 = v3 > v2; float a1 = p1 ? v3 : v2; int n1 = p1 ? (i3) : (i2); \
  bool p2 = v5 > v4; float a2 = p2 ? v5 : v4; int n2 = p2 ? (i5) : (i4); \
  bool p3 = v7 > v6; float a3 = p3 ? v7 : v6; int n3 = p3 ? (i7) : (i6); \
  bool r0 = a1 > a0; float bb0 = r0 ? a1 : a0; int m0 = r0 ? n1 : n0; \
  bool r1 = a3 > a2; float bb1 = r1 ? a3 : a2; int m1 = r1 ? n3 : n2; \
  bool s0 = bb1 > bb0; float gg = s0 ? bb1 : bb0; int w0 = s0 ? m1 : m0; \
  bool u0 = gg > bv; bv = u0 ? gg : bv; bi = u0 ? w0 : bi; }

// ============================ ASM text pieces ============================
#define FG(A,B,C,D,E0,E1,E2,E3,OP) \
  "v_readlane_b32 s56, %[x], " #A "\n\t" \
  "v_readlane_b32 s57, %[x], " #B "\n\t" \
  "v_readlane_b32 s58, %[x], " #C "\n\t" \
  "v_readlane_b32 s59, %[x], " #D "\n\t" \
  #OP " v20, s56, v" #E0 "\n\t" \
  #OP " v21, s57, v" #E1 "\n\t" \
  #OP " v22, s58, v" #E2 "\n\t" \
  #OP " v23, s59, v" #E3 "\n\t"

#define FWD_DOT \
  FG(0,1,2,3,64,65,66,67,v_mul_f32)      FG(4,5,6,7,68,69,70,71,v_fmac_f32) \
  FG(8,9,10,11,72,73,74,75,v_fmac_f32)   FG(12,13,14,15,76,77,78,79,v_fmac_f32) \
  FG(16,17,18,19,80,81,82,83,v_fmac_f32) FG(20,21,22,23,84,85,86,87,v_fmac_f32) \
  FG(24,25,26,27,88,89,90,91,v_fmac_f32) FG(28,29,30,31,92,93,94,95,v_fmac_f32) \
  FG(32,33,34,35,96,97,98,99,v_fmac_f32) FG(36,37,38,39,100,101,102,103,v_fmac_f32) \
  FG(40,41,42,43,104,105,106,107,v_fmac_f32) FG(44,45,46,47,108,109,110,111,v_fmac_f32) \
  FG(48,49,50,51,112,113,114,115,v_fmac_f32) FG(52,53,54,55,116,117,118,119,v_fmac_f32) \
  FG(56,57,58,59,120,121,122,123,v_fmac_f32) FG(60,61,62,63,124,125,126,127,v_fmac_f32)

#define VG(A,B,C,D,E0,E1,E2,E3,RED) \
  "v_readlane_b32 s56, %[x], " #A "\n\t" \
  "v_readlane_b32 s57, %[x], " #B "\n\t" \
  "v_readlane_b32 s58, %[x], " #C "\n\t" \
  "v_readlane_b32 s59, %[x], " #D "\n\t" \
  "v_add_f32 v16, s56, v" #E0 "\n\t" \
  "v_add_f32 v17, s57, v" #E1 "\n\t" \
  "v_add_f32 v18, s58, v" #E2 "\n\t" \
  "v_add_f32 v19, s59, v" #E3 "\n\t" \
  "v_max3_f32 v16, v16, v17, v18\n\t" \
  RED "\n\t"

#define VIT_DOT \
  VG(0,1,2,3,64,65,66,67,"v_max_f32 v20, v16, v19") \
  VG(4,5,6,7,68,69,70,71,"v_max3_f32 v20, v20, v16, v19") \
  VG(8,9,10,11,72,73,74,75,"v_max3_f32 v20, v20, v16, v19") \
  VG(12,13,14,15,76,77,78,79,"v_max3_f32 v20, v20, v16, v19") \
  VG(16,17,18,19,80,81,82,83,"v_max3_f32 v20, v20, v16, v19") \
  VG(20,21,22,23,84,85,86,87,"v_max3_f32 v20, v20, v16, v19") \
  VG(24,25,26,27,88,89,90,91,"v_max3_f32 v20, v20, v16, v19") \
  VG(28,29,30,31,92,93,94,95,"v_max3_f32 v20, v20, v16, v19") \
  VG(32,33,34,35,96,97,98,99,"v_max3_f32 v20, v20, v16, v19") \
  VG(36,37,38,39,100,101,102,103,"v_max3_f32 v20, v20, v16, v19") \
  VG(40,41,42,43,104,105,106,107,"v_max3_f32 v20, v20, v16, v19") \
  VG(44,45,46,47,108,109,110,111,"v_max3_f32 v20, v20, v16, v19") \
  VG(48,49,50,51,112,113,114,115,"v_max3_f32 v20, v20, v16, v19") \
  VG(52,53,54,55,116,117,118,119,"v_max3_f32 v20, v20, v16, v19") \
  VG(56,57,58,59,120,121,122,123,"v_max3_f32 v20, v20, v16, v19") \
  VG(60,61,62,63,124,125,126,127,"v_max3_f32 v20, v20, v16, v19")

#define AGLD(N,OFF) "global_load_dword v" #N ", v13, %[tp] offset:" #OFF "\n\t"
#define AGLE(N,OFF) "global_load_dword v" #N ", v12, %[ep] offset:" #OFF "\n\t"
#define AGLM(N,OFF) "global_load_dword v" #N ", v14, %[mp] offset:" #OFF "\n\t"

#define ELOADS \
  AGLD(64,0) AGLD(65,256) AGLD(66,512) AGLD(67,768) AGLD(68,1024) AGLD(69,1280) \
  AGLD(70,1536) AGLD(71,1792) AGLD(72,2048) AGLD(73,2304) AGLD(74,2560) AGLD(75,2816) \
  AGLD(76,3072) AGLD(77,3328) AGLD(78,3584) AGLD(79,3840) \
  "v_add_u32 v13, 0x1000, v13\n\t" \
  AGLD(80,0) AGLD(81,256) AGLD(82,512) AGLD(83,768) AGLD(84,1024) AGLD(85,1280) \
  AGLD(86,1536) AGLD(87,1792) AGLD(88,2048) AGLD(89,2304) AGLD(90,2560) AGLD(91,2816) \
  AGLD(92,3072) AGLD(93,3328) AGLD(94,3584) AGLD(95,3840) \
  "v_add_u32 v13, 0x1000, v13\n\t" \
  AGLD(96,0) AGLD(97,256) AGLD(98,512) AGLD(99,768) AGLD(100,1024) AGLD(101,1280) \
  AGLD(102,1536) AGLD(103,1792) AGLD(104,2048) AGLD(105,2304) AGLD(106,2560) AGLD(107,2816) \
  AGLD(108,3072) AGLD(109,3328) AGLD(110,3584) AGLD(111,3840) \
  "v_add_u32 v13, 0x1000, v13\n\t" \
  AGLD(112,0) AGLD(113,256) AGLD(114,512) AGLD(115,768) AGLD(116,1024) AGLD(117,1280) \
  AGLD(118,1536) AGLD(119,1792) AGLD(120,2048) AGLD(121,2304) AGLD(122,2560) AGLD(123,2816) \
  AGLD(124,3072) AGLD(125,3328) AGLD(126,3584) AGLD(127,3840)

#define AMUL(N) "v_mul_f32 v" #N ", 0x3fb8aa3b, v" #N "\n\t"
#define AEXI(N) "v_exp_f32 v" #N ", v" #N "\n\t"
#define EEXPALL \
  AMUL(64) AMUL(65) AMUL(66) AMUL(67) AMUL(68) AMUL(69) AMUL(70) AMUL(71) \
  AMUL(72) AMUL(73) AMUL(74) AMUL(75) AMUL(76) AMUL(77) AMUL(78) AMUL(79) \
  AMUL(80) AMUL(81) AMUL(82) AMUL(83) AMUL(84) AMUL(85) AMUL(86) AMUL(87) \
  AMUL(88) AMUL(89) AMUL(90) AMUL(91) AMUL(92) AMUL(93) AMUL(94) AMUL(95) \
  AMUL(96) AMUL(97) AMUL(98) AMUL(99) AMUL(100) AMUL(101) AMUL(102) AMUL(103) \
  AMUL(104) AMUL(105) AMUL(106) AMUL(107) AMUL(108) AMUL(109) AMUL(110) AMUL(111) \
  AMUL(112) AMUL(113) AMUL(114) AMUL(115) AMUL(116) AMUL(117) AMUL(118) AMUL(119) \
  AMUL(120) AMUL(121) AMUL(122) AMUL(123) AMUL(124) AMUL(125) AMUL(126) AMUL(127) \
  AEXI(64) AEXI(65) AEXI(66) AEXI(67) AEXI(68) AEXI(69) AEXI(70) AEXI(71) \
  AEXI(72) AEXI(73) AEXI(74) AEXI(75) AEXI(76) AEXI(77) AEXI(78) AEXI(79) \
  AEXI(80) AEXI(81) AEXI(82) AEXI(83) AEXI(84) AEXI(85) AEXI(86) AEXI(87) \
  AEXI(88) AEXI(89) AEXI(90) AEXI(91) AEXI(92) AEXI(93) AEXI(94) AEXI(95) \
  AEXI(96) AEXI(97) AEXI(98) AEXI(99) AEXI(100) AEXI(101) AEXI(102) AEXI(103) \
  AEXI(104) AEXI(105) AEXI(106) AEXI(107) AEXI(108) AEXI(109) AEXI(110) AEXI(111) \
  AEXI(112) AEXI(113) AEXI(114) AEXI(115) AEXI(116) AEXI(117) AEXI(118) AEXI(119) \
  AEXI(120) AEXI(121) AEXI(122) AEXI(123) AEXI(124) AEXI(125) AEXI(126) AEXI(127)

#define EMIS16 \
  AGLE(40,0) AGLE(41,256) AGLE(42,512) AGLE(43,768) AGLE(44,1024) AGLE(45,1280) \
  AGLE(46,1536) AGLE(47,1792) AGLE(48,2048) AGLE(49,2304) AGLE(50,2560) AGLE(51,2816) \
  AGLE(52,3072) AGLE(53,3328) AGLE(54,3584) AGLE(55,3840)
#define EMIS8 \
  AGLE(40,0) AGLE(41,256) AGLE(42,512) AGLE(43,768) AGLE(44,1024) AGLE(45,1280) \
  AGLE(46,1536) AGLE(47,1792)
#define MASK16 \
  AGLM(128,0) AGLM(129,4) AGLM(130,8) AGLM(131,12) AGLM(132,16) AGLM(133,20) \
  AGLM(134,24) AGLM(135,28) AGLM(136,32) AGLM(137,36) AGLM(138,40) AGLM(139,44) \
  AGLM(140,48) AGLM(141,52) AGLM(142,56) AGLM(143,60)
#define MASK8 \
  AGLM(128,0) AGLM(129,4) AGLM(130,8) AGLM(131,12) AGLM(132,16) AGLM(133,20) \
  AGLM(134,24) AGLM(135,28)

#define AEM(D,R) "v_mul_f32 v" #D ", 0x3fb8aa3b, v" #R "\n\t"
#define EMEXP16 \
  AEM(24,40) AEM(25,41) AEM(26,42) AEM(27,43) AEM(28,44) AEM(29,45) AEM(30,46) AEM(31,47) \
  AEM(32,48) AEM(33,49) AEM(34,50) AEM(35,51) AEM(36,52) AEM(37,53) AEM(38,54) AEM(39,55) \
  AEXI(24) AEXI(25) AEXI(26) AEXI(27) AEXI(28) AEXI(29) AEXI(30) AEXI(31) \
  AEXI(32) AEXI(33) AEXI(34) AEXI(35) AEXI(36) AEXI(37) AEXI(38) AEXI(39)
#define EMEXP8 \
  AEM(24,40) AEM(25,41) AEM(26,42) AEM(27,43) AEM(28,44) AEM(29,45) AEM(30,46) AEM(31,47) \
  AEXI(24) AEXI(25) AEXI(26) AEXI(27) AEXI(28) AEXI(29) AEXI(30) AEXI(31)

#define AFSTEP(MR,EV) \
  "v_cmp_ne_u32 vcc, 0, v" #MR "\n\t" \
  FWD_DOT \
  "v_add_f32 v16, v20, v21\n\t" \
  "v_add_f32 v17, v22, v23\n\t" \
  "v_add_f32 v16, v16, v17\n\t" \
  "v_mul_f32 v16, v16, v" #EV "\n\t" \
  "v_cndmask_b32 %[x], %[x], v16, vcc\n\t"

#define RNRM \
  "v_mov_b32 v17, %[x]\n\t" \
  "ds_swizzle_b32 v18, v17 offset:0x041F\n\t" \
  "s_waitcnt lgkmcnt(0)\n\t" \
  "v_max_f32 v17, v17, v18\n\t" \
  "ds_swizzle_b32 v18, v17 offset:0x081F\n\t" \
  "s_waitcnt lgkmcnt(0)\n\t" \
  "v_max_f32 v17, v17, v18\n\t" \
  "ds_swizzle_b32 v18, v17 offset:0x101F\n\t" \
  "s_waitcnt lgkmcnt(0)\n\t" \
  "v_max_f32 v17, v17, v18\n\t" \
  "ds_swizzle_b32 v18, v17 offset:0x201F\n\t" \
  "s_waitcnt lgkmcnt(0)\n\t" \
  "v_max_f32 v17, v17, v18\n\t" \
  "ds_swizzle_b32 v18, v17 offset:0x401F\n\t" \
  "s_waitcnt lgkmcnt(0)\n\t" \
  "v_max_f32 v17, v17, v18\n\t" \
  "v_readlane_b32 s56, v17, 0\n\t" \
  "v_readlane_b32 s57, v17, 32\n\t" \
  "v_mov_b32 v18, s57\n\t" \
  "v_max_f32 v18, s56, v18\n\t" \
  "v_readlane_b32 s56, v18, 0\n\t"

#define AFSTEPR(MR,EV) \
  "v_cmp_ne_u32 vcc, 0, v" #MR "\n\t" \
  FWD_DOT \
  "v_add_f32 v16, v20, v21\n\t" \
  "v_add_f32 v17, v22, v23\n\t" \
  "v_add_f32 v16, v16, v17\n\t" \
  "v_mul_f32 v16, v16, v" #EV "\n\t" \
  RNRM \
  "v_cndmask_b32 %[x], %[x], v16, vcc\n\t" \
  "v_rcp_f32 v18, s56\n\t" \
  "v_log_f32 v19, s56\n\t" \
  "v_mul_f32 %[x], %[x], v18\n\t" \
  "v_fmac_f32 %[off], 0x3f317218, v19\n\t"

#define AVSTEP(MR,EV) \
  "v_cmp_ne_u32 vcc, 0, v" #MR "\n\t" \
  VIT_DOT \
  "v_add_f32 v16, v20, v" #EV "\n\t" \
  "v_cndmask_b32 %[x], %[x], v16, vcc\n\t"

#define CLOBS \
  "v11","v12","v13","v14","v16","v17","v18","v19","v20","v21","v22","v23", \
  "v24","v25","v26","v27","v28","v29","v30","v31","v32","v33","v34","v35", \
  "v36","v37","v38","v39","v40","v41","v42","v43","v44","v45","v46","v47", \
  "v48","v49","v50","v51","v52","v53","v54","v55", \
  "v64","v65","v66","v67","v68","v69","v70","v71","v72","v73","v74","v75", \
  "v76","v77","v78","v79","v80","v81","v82","v83","v84","v85","v86","v87", \
  "v88","v89","v90","v91","v92","v93","v94","v95","v96","v97","v98","v99", \
  "v100","v101","v102","v103","v104","v105","v106","v107","v108","v109", \
  "v110","v111","v112","v113","v114","v115","v116","v117","v118","v119", \
  "v120","v121","v122","v123","v124","v125","v126","v127","v128","v129", \
  "v130","v131","v132","v133","v134","v135","v136","v137","v138","v139", \
  "v140","v141","v142","v143", \
  "s55","s56","s57","s58","s59","vcc","scc","memory"

__global__ __launch_bounds__(512)
__attribute__((amdgpu_waves_per_eu(1, 2)))
void crf_mega_kernel(
    const float* __restrict__ em, const int* __restrict__ mask,
    const float* __restrict__ trans, const int* __restrict__ tags,
    float* __restrict__ out_dec, float* ll_sum, int* match, int* maskSum) {

  __shared__ float Ecol[KK * CS];               // exp(T) columns (C++ head/t1)
  __shared__ float Ccol[KK * CS];               // raw T columns (tail + phase B)
  __shared__ __align__(16) float ckw[64][KK];   // vit deltas every 16 steps
  __shared__ float fin[KK];                     // final vit delta (t=1023)
  __shared__ unsigned char mrow[TT];
  __shared__ unsigned char bpl[TT][KK];
  __shared__ unsigned char segm[32][KK];
  __shared__ unsigned char bs[40];
  __shared__ int redm[32];

  const int b = blockIdx.x;
  const int tid = threadIdx.x;
  const int wv = tid >> 6;
  const int j = tid & 63;
  const int jb65 = j * CS;

  const float* emb = em + (size_t)b * TT * KK;
  const int* mb = mask + (size_t)b * TT;
  const int* tgb = tags + (size_t)b * TT;

  for (int t = tid; t < TT; t += 512) mrow[t] = (unsigned char)(mb[t] ? 1 : 0);
  if (wv == 0) {
#pragma unroll 4
    for (int i = 0; i < KK; ++i) Ecol[jb65 + i] = __expf(trans[i * KK + j]);
  } else if (wv == 1) {
#pragma unroll 4
    for (int i = 0; i < KK; ++i) Ccol[jb65 + i] = trans[i * KK + j];
  }
  __syncthreads();  // B0

  if (wv == 0) {
    // =========================== FORWARD (wave 0) ===========================
    float raw = emb[j];
    float x, offset;
    {  // t = 1 special
      float m0 = wavemax(raw);
      offset = m0;
      float s = __expf(raw - m0);
      int eb = jb65; asm volatile("" : "+v"(eb));
      float q0 = 0.f, q1 = 0.f, q2 = 0.f, q3 = 0.f;
      CFQALL(s)
      float q = (q0 + q1) + (q2 + q3);
      q *= __expf(emb[KK + j]);
      x = mrow[1] ? q : s;
    }
    // head t = 2..7 (no renorm in range)
    for (int t = 2; t <= 7; ++t) {
      float e = __expf(emb[(size_t)t * KK + j]);
      int m = mrow[t];
      CFWD_STEP(t, e, m)
    }
    // asm chain t = 8..1023 (63 x 16-step iters + 8-step epilogue)
    asm volatile(
      "s_mov_b32 s55, 0\n\t"
      "v_mov_b32 v12, %[vo]\n\t"
      "v_mov_b32 v13, %[jo]\n\t"
      "v_mov_b32 v14, 32\n\t"
      ELOADS
      "s_waitcnt vmcnt(0)\n\t"
      EEXPALL
      "9:\n\t"
      MASK16
      EMIS16
      "v_add_u32 v12, 0x1000, v12\n\t"
      "v_add_u32 v14, 64, v14\n\t"
      "s_waitcnt vmcnt(0)\n\t"
      EMEXP16
      AFSTEPR(128,24) AFSTEP(129,25) AFSTEP(130,26) AFSTEP(131,27)
      AFSTEP(132,28)  AFSTEP(133,29) AFSTEP(134,30) AFSTEP(135,31)
      AFSTEPR(136,32) AFSTEP(137,33) AFSTEP(138,34) AFSTEP(139,35)
      AFSTEP(140,36)  AFSTEP(141,37) AFSTEP(142,38) AFSTEP(143,39)
      "s_add_u32 s55, s55, 1\n\t"
      "s_cmp_lt_u32 s55, 63\n\t"
      "s_cbranch_scc1 9b\n\t"
      MASK8
      EMIS8
      "s_waitcnt vmcnt(0)\n\t"
      EMEXP8
      AFSTEPR(128,24) AFSTEP(129,25) AFSTEP(130,26) AFSTEP(131,27)
      AFSTEP(132,28)  AFSTEP(133,29) AFSTEP(134,30) AFSTEP(135,31)
      "s_waitcnt vmcnt(0) lgkmcnt(0)\n\t"
      : [x]"+v"(x), [off]"+v"(offset)
      : [ep]"s"(emb), [mp]"s"(mb), [tp]"s"(trans),
        [vo]"v"(2048 + 4 * j), [jo]"v"(4 * j)
      : CLOBS);

    float ssum = x;
#pragma unroll
    for (int off = 1; off <= 32; off <<= 1) ssum += __shfl_xor(ssum, off);
    if (tid == 0) atomicAdd(ll_sum, -(offset + __logf(ssum)));

  } else if (wv == 1) {
    // ====================== VITERBI max-only (wave 1) ======================
    float x = emb[j];
    unsigned ckoff = (unsigned)(unsigned long long)(&ckw[1][j]);
    // asm chain t = 1..1016 (63 x 16-step iters + 8-step epilogue);
    // ds_write delta to ckw slot m+1 after each iter (t = 16(m+1)).
    asm volatile(
      "s_mov_b32 s55, 0\n\t"
      "v_mov_b32 v11, %[ck]\n\t"
      "v_mov_b32 v12, %[vo]\n\t"
      "v_mov_b32 v13, %[jo]\n\t"
      "v_mov_b32 v14, 4\n\t"
      ELOADS
      "s_waitcnt vmcnt(0)\n\t"
      "8:\n\t"
      MASK16
      EMIS16
      "v_add_u32 v12, 0x1000, v12\n\t"
      "v_add_u32 v14, 64, v14\n\t"
      "s_waitcnt vmcnt(0)\n\t"
      AVSTEP(128,40) AVSTEP(129,41) AVSTEP(130,42) AVSTEP(131,43)
      AVSTEP(132,44) AVSTEP(133,45) AVSTEP(134,46) AVSTEP(135,47)
      AVSTEP(136,48) AVSTEP(137,49) AVSTEP(138,50) AVSTEP(139,51)
      AVSTEP(140,52) AVSTEP(141,53) AVSTEP(142,54) AVSTEP(143,55)
      "ds_write_b32 v11, %[x]\n\t"
      "v_add_u32 v11, 0x100, v11\n\t"
      "s_add_u32 s55, s55, 1\n\t"
      "s_cmp_lt_u32 s55, 63\n\t"
      "s_cbranch_scc1 8b\n\t"
      MASK8
      EMIS8
      "s_waitcnt vmcnt(0)\n\t"
      AVSTEP(128,40) AVSTEP(129,41) AVSTEP(130,42) AVSTEP(131,43)
      AVSTEP(132,44) AVSTEP(133,45) AVSTEP(134,46) AVSTEP(135,47)
      "s_waitcnt vmcnt(0) lgkmcnt(0)\n\t"
      : [x]"+v"(x)
      : [ep]"s"(emb), [mp]"s"(mb), [tp]"s"(trans),
        [vo]"v"(256 + 4 * j), [jo]"v"(4 * j), [ck]"v"(ckoff)
      : CLOBS);
    // C++ tail t = 1017..1023 (7 steps)
    for (int t = TT - 7; t <= TT - 1; ++t) {
      float e = emb[(size_t)t * KK + j];
      int m = mrow[t];
      CVIT_STEP(t, e, m)
    }
    fin[j] = x;

  } else if (wv == 2) {
    // ========================= PATH SCORE (wave 2) =========================
    float acc = 0.f;
    int cnt = 0;
    for (int t = j; t < TT; t += 64) {
      if (mb[t]) {
        int tg = tgb[t];
        acc += emb[(size_t)t * KK + tg];
        cnt += 1;
        if (t >= 1) acc += trans[tgb[t - 1] * KK + tg];
      }
    }
#pragma unroll
    for (int off = 1; off <= 32; off <<= 1) {
      acc += __shfl_xor(acc, off);
      cnt += __shfl_xor(cnt, off);
    }
    if (j == 0) { atomicAdd(ll_sum, acc); atomicAdd(maskSum, cnt); }
  }
  // waves 3-7 fall through.

  __syncthreads();  // B1 — phase boundary (orders ckw, fin, Ccol)

  // ====== PHASE B: per-segment argmax recompute (8 waves x 4 segments) ======
#pragma unroll 1
  for (int kk = 0; kk < 4; ++kk) {
    int s = wv + 8 * kk;
    int tS = 32 * s + 1;
    int tE = (s == 31) ? (TT - 1) : (32 * s + 32);
    float x2 = (s == 0) ? emb[j] : ckw[2 * s][j];
    float e_nx = emb[(size_t)tS * KK + j];
#pragma unroll 1
    for (int t = tS; t <= tE; ++t) {
      float e = e_nx;
      if (t < tE) e_nx = emb[(size_t)(t + 1) * KK + j];
      int db = jb65; asm volatile("" : "+v"(db));
      float bv = -__builtin_inff(); int bi = 0;
      AG(0, 1, 2, 3, 4, 5, 6, 7)        AG(8, 9, 10, 11, 12, 13, 14, 15)
      AG(16, 17, 18, 19, 20, 21, 22, 23) AG(24, 25, 26, 27, 28, 29, 30, 31)
      AG(32, 33, 34, 35, 36, 37, 38, 39) AG(40, 41, 42, 43, 44, 45, 46, 47)
      AG(48, 49, 50, 51, 52, 53, 54, 55) AG(56, 57, 58, 59, 60, 61, 62, 63)
      int m = mrow[t];
      float nd = m ? (bv + e) : x2;
      int bp = m ? bi : j;
      bpl[t][j] = (unsigned char)bp;
      x2 = nd;
    }
  }
  __syncthreads();  // B2

  // ---- compose 32-step segment maps (4 chains per thread, ILP) ----
  {
    int j0 = tid & 63;
    int sg = tid >> 6;
    int xs[4]; int tS[4], tE[4];
#pragma unroll
    for (int kk = 0; kk < 4; ++kk) {
      int s = sg + 8 * kk;
      xs[kk] = j0;
      tS[kk] = 32 * s + 1;
      tE[kk] = (s == 31) ? (TT - 1) : (32 * s + 32);
    }
    for (int q = 0; q < 32; ++q) {
#pragma unroll
      for (int kk = 0; kk < 4; ++kk) {
        int t = tE[kk] - q;
        if (t >= tS[kk]) xs[kk] = bpl[t][xs[kk]];
      }
    }
#pragma unroll
    for (int kk = 0; kk < 4; ++kk) segm[sg + 8 * kk][j0] = (unsigned char)xs[kk];
  }
  __syncthreads();  // B3

  if (tid == 0) {   // last-tag argmax (strict >, first max) + boundary walk
    float bd = fin[0];
    int lt = 0;
    for (int i = 1; i < KK; ++i) {
      float v2 = fin[i];
      if (v2 > bd) { bd = v2; lt = i; }
    }
    bs[32] = (unsigned char)lt;
    for (int s = 31; s >= 0; --s) bs[s] = segm[s][bs[s + 1]];
  }
  __syncthreads();  // B4

  if (tid < 32) {   // per-segment backtrace
    int s = tid;
    int x = bs[s + 1];
    int cnt = 0;
    int tEnd = (s == 31) ? (TT - 1) : (32 * s + 32);
    if (s == 31) {
      int m = mrow[TT - 1];
      out_dec[(size_t)b * TT + TT - 1] = (float)(m ? x : 0);
      cnt += (m && x == tgb[TT - 1]);
    }
    for (int t = tEnd; t >= 32 * s + 1; --t) {
      x = bpl[t][x];
      int m2 = mrow[t - 1];
      out_dec[(size_t)b * TT + t - 1] = (float)(m2 ? x : 0);
      cnt += (m2 && x == tgb[t - 1]);
    }
    redm[s] = cnt;
  }
  __syncthreads();  // B5
  if (tid == 0) {
    int c = 0;
    for (int s = 0; s < 32; ++s) c += redm[s];
    atomicAdd(match, c);
  }
}

__global__ void finalize_kernel(const float* ll_sum, const int* match,
                                const int* maskSum, float* d_out) {
  d_out[0] = -(*ll_sum) / (float)BB;
  d_out[1 + BB * TT] = (float)(*match) / (float)(*maskSum);
}

extern "C" void kernel_launch(void* const* d_in, const int* in_sizes, int n_in,
                              void* d_out, int out_size, void* d_ws, size_t ws_size,
                              hipStream_t stream) {
  const float* em = (const float*)d_in[0];
  const int* tags = (const int*)d_in[1];
  const int* mask = (const int*)d_in[2];       // bool -> int32 on device
  const float* trans = (const float*)d_in[3];
  float* out = (float*)d_out;

  float* ll_sum = (float*)d_ws;
  int* match = (int*)((char*)d_ws + 4);
  int* maskSum = (int*)((char*)d_ws + 8);

  hipMemsetAsync(d_ws, 0, 12, stream);
  crf_mega_kernel<<<BB, 512, 0, stream>>>(em, mask, trans, tags, out + 1,
                                          ll_sum, match, maskSum);
  finalize_kernel<<<1, 1, 0, stream>>>(ll_sum, match, maskSum, out);
}